// Round 1
// baseline (299.327 us; speedup 1.0000x reference)
//
#include <hip/hip_runtime.h>
#include <hip/hip_fp16.h>

typedef __attribute__((ext_vector_type(8))) short short8;
typedef __attribute__((ext_vector_type(4))) float f32x4;

#define NTT 1000
#define NSB 500
#define WARM 639

__device__ __forceinline__ float fsig(float x) {
  return __builtin_amdgcn_rcpf(1.f + __expf(-x));
}
__device__ __forceinline__ float ftanh(float x) {
  float ax = fabsf(x);
  float e = __expf(-2.f * ax);
  float r = (1.f - e) * __builtin_amdgcn_rcpf(1.f + e);
  return x < 0.f ? -r : r;
}
__device__ __forceinline__ unsigned short f2bf(float f) {
  unsigned int u = __float_as_uint(f);
  u += 0x7fffu + ((u >> 16) & 1u);
  return (unsigned short)(u >> 16);
}
__device__ __forceinline__ float h2f(unsigned short u) {
  __half_raw hr; hr.x = u;
  return __half2float((__half)hr);
}

// ------------- prep: Wt2 (256x48 f32) -> bf16 transposed [48][264] -------------
__global__ void prep_bt_kernel(const float* __restrict__ Wt2,
                               unsigned short* __restrict__ BT) {
  int i = blockIdx.x * 256 + threadIdx.x;
  if (i < 48 * 256) {
    int o = i >> 8, k = i & 255;
    BT[o * 264 + k] = f2bf(Wt2[k * 48 + o]);
  }
}

// ------------- static per-basin params (one block per basin) -------------
__global__ __launch_bounds__(256) void static_kernel(
    const float* __restrict__ xc,
    const float* __restrict__ Wr1, const float* __restrict__ br1,
    const float* __restrict__ Wr2, const float* __restrict__ br2,
    const float* __restrict__ Ww1, const float* __restrict__ bw1,
    const float* __restrict__ Ww2, const float* __restrict__ bw2,
    const float* __restrict__ Wt1, const float* __restrict__ bt1,
    float* __restrict__ c_g, float* __restrict__ params,
    float* __restrict__ rg)
{
  int s = blockIdx.x, tid = threadIdx.x;
  __shared__ float xcs[32];
  __shared__ float hw[256], hr[256];
  __shared__ float wout[112], rout[256];
  if (tid < 32) xcs[tid] = xc[s * 32 + tid];
  __syncthreads();
  {
    float aw = bw1[tid], ar = br1[tid], ac = bt1[tid];
    #pragma unroll 8
    for (int g = 0; g < 32; ++g) {
      float v = xcs[g];
      aw = fmaf(v, Ww1[g * 256 + tid], aw);
      ar = fmaf(v, Wr1[g * 256 + tid], ar);
      ac = fmaf(v, Wt1[(6 + g) * 256 + tid], ac);
    }
    hw[tid] = ftanh(aw);
    hr[tid] = ftanh(ar);
    c_g[s * 256 + tid] = ac;   // time-invariant part of layer-1 preact
  }
  __syncthreads();
  {
    float acc = br2[tid];
    #pragma unroll 8
    for (int k = 0; k < 256; ++k) acc = fmaf(hr[k], Wr2[k * 256 + tid], acc);
    rout[tid] = acc;
  }
  if (tid < 112) {
    float acc = bw2[tid];
    #pragma unroll 8
    for (int k = 0; k < 256; ++k) acc = fmaf(hw[k], Ww2[k * 112 + tid], acc);
    wout[tid] = acc;
  }
  __syncthreads();
  if (tid < 16) {
    int h = tid;
    float* P = params + (s * 16 + h) * 6;
    P[0] = fsig(wout[h * 7 + 0]);           // kp
    P[1] = fsig(wout[h * 7 + 1]);           // ksf
    P[2] = fsig(wout[h * 7 + 2]);           // kg
    P[3] = fsig(wout[h * 7 + 3]);           // gr
    P[4] = __expf(wout[h * 7 + 4]);         // gL
    P[5] = fmaxf(wout[h * 7 + 5], 0.f);     // qb
    // ga = softmax over h of wout[.*7+6]
    float m = -1e30f;
    for (int k = 0; k < 16; ++k) m = fmaxf(m, wout[k * 7 + 6]);
    float den = 0.f;
    for (int k = 0; k < 16; ++k) den += __expf(wout[k * 7 + 6] - m);
    float ga = __expf(wout[h * 7 + 6] - m) * __builtin_amdgcn_rcpf(den);
    // r = softmax over j, fused with ga -> rg
    float rm = -1e30f;
    for (int j = 0; j < 16; ++j) rm = fmaxf(rm, rout[h * 16 + j]);
    float rden = 0.f;
    for (int j = 0; j < 16; ++j) rden += __expf(rout[h * 16 + j] - rm);
    float sc = ga * __builtin_amdgcn_rcpf(rden);
    for (int j = 0; j < 16; ++j)
      rg[(s * 16 + h) * 16 + j] = __expf(rout[h * 16 + j] - rm) * sc;
  }
}

// ------------- time-varying MLP: layer1 fp32 (K=6) + layer2 bf16 MFMA -------------
__global__ __launch_bounds__(256, 2) void tv_kernel(
    const float* __restrict__ x, const float* __restrict__ Wt1,
    const float* __restrict__ bt2, const float* __restrict__ c_g,
    const unsigned short* __restrict__ BTg,
    __half* __restrict__ pliP, __half* __restrict__ fmP,
    __half* __restrict__ evP, float* __restrict__ psP)
{
  int s = blockIdx.x;
  int t0 = blockIdx.y * 64;
  int tid = threadIdx.x;
  __shared__ unsigned short Abuf[64 * 264];   // hidden bf16, [t][k] pitch 264
  __shared__ unsigned short Bbuf[48 * 264];   // Wt2^T bf16, [n][k] pitch 264
  __shared__ float xl[64][6];

  for (int i = tid; i < 48 * 264; i += 256) Bbuf[i] = BTg[i];
  for (int i = tid; i < 64 * 6; i += 256) {
    int tt = i / 6, c = i % 6;
    int t = t0 + tt;
    xl[tt][c] = (t < NTT) ? x[((size_t)t * NSB + s) * 6 + c] : 0.f;
  }
  __syncthreads();

  // phase 1: hidden[t][j] = tanh(c_s[j] + sum_c x[t,c]*Wt1[c][j])
  {
    int j = tid;
    float w0 = Wt1[j], w1 = Wt1[256 + j], w2 = Wt1[512 + j],
          w3 = Wt1[768 + j], w4 = Wt1[1024 + j], w5 = Wt1[1280 + j];
    float cj = c_g[s * 256 + j];
    #pragma unroll 4
    for (int tt = 0; tt < 64; ++tt) {
      float p = cj;
      p = fmaf(xl[tt][0], w0, p);
      p = fmaf(xl[tt][1], w1, p);
      p = fmaf(xl[tt][2], w2, p);
      p = fmaf(xl[tt][3], w3, p);
      p = fmaf(xl[tt][4], w4, p);
      p = fmaf(xl[tt][5], w5, p);
      Abuf[tt * 264 + j] = f2bf(ftanh(p));
    }
  }
  __syncthreads();

  // phase 2: v[16 samples x 48] per wave via MFMA 16x16x32 bf16
  int wv = tid >> 6, l = tid & 63;
  int col = l & 15;
  int kb = (l >> 4) * 8;
  f32x4 acc0 = {0.f, 0.f, 0.f, 0.f}, acc1 = acc0, acc2 = acc0;
  const unsigned short* Arow = &Abuf[(wv * 16 + col) * 264 + kb];
  const unsigned short* B0 = &Bbuf[(0 + col) * 264 + kb];
  const unsigned short* B1 = &Bbuf[(16 + col) * 264 + kb];
  const unsigned short* B2 = &Bbuf[(32 + col) * 264 + kb];
  #pragma unroll
  for (int ks = 0; ks < 8; ++ks) {
    short8 a  = *(const short8*)(Arow + ks * 32);
    short8 b0 = *(const short8*)(B0 + ks * 32);
    short8 b1 = *(const short8*)(B1 + ks * 32);
    short8 b2 = *(const short8*)(B2 + ks * 32);
    acc0 = __builtin_amdgcn_mfma_f32_16x16x32_bf16(a, b0, acc0, 0, 0, 0);
    acc1 = __builtin_amdgcn_mfma_f32_16x16x32_bf16(a, b1, acc1, 0, 0, 0);
    acc2 = __builtin_amdgcn_mfma_f32_16x16x32_bf16(a, b2, acc2, 0, 0, 0);
  }
  // epilogue: C[row][col], row=(l>>4)*4+i, col=l&15 (guide §3, m89-verified)
  float b2_0 = bt2[col], b2_1 = bt2[16 + col], b2_2 = bt2[32 + col];
  #pragma unroll
  for (int i = 0; i < 4; ++i) {
    int r = wv * 16 + ((l >> 4) * 4) + i;
    int t = t0 + r;
    if (t >= NTT) continue;
    float Prc = xl[r][0], Evv = xl[r][1];
    float vp = fsig(0.5f * (xl[r][2] + xl[r][3]));
    float plv = Prc * vp;
    size_t base = (size_t)t * 8000 + s * 16;
    float vv0 = acc0[i] + b2_0, vv1 = acc1[i] + b2_1, vv2 = acc2[i] + b2_2;
    #pragma unroll
    for (int nt = 0; nt < 3; ++nt) {
      float v = (nt == 0) ? vv0 : (nt == 1) ? vv1 : vv2;
      int o = nt * 16 + col;
      int h = o / 3, p = o - h * 3;
      if (p == 0)      pliP[base + h] = __float2half(plv * fsig(v));       // pl*fi
      else if (p == 1) fmP [base + h] = __float2half(fmaxf(v, 0.f));       // fm
      else             evP [base + h] = __float2half(Evv * __expf(v));     // Ev
    }
  }
  if (tid < 64) {
    int t = t0 + tid;
    if (t < NTT) {
      float vp = fsig(0.5f * (xl[tid][2] + xl[tid][3]));
      psP[t * NSB + s] = xl[tid][0] * (1.f - vp);
    }
  }
}

// ------------- sequential bucket scan, 8000 chains, reg-prefetched -------------
struct Chunk {
  float ps[16];
  unsigned short pli[16], fm[16], ev[16];
};

__device__ __forceinline__ void load_chunk(
    Chunk& c, int tb, int s, int tid,
    const unsigned short* pliP, const unsigned short* fmP,
    const unsigned short* evP, const float* psP)
{
  #pragma unroll
  for (int u = 0; u < 16; ++u) {
    int t = tb + u; t = t < NTT ? t : NTT - 1;   // clamp: values discarded
    size_t off = (size_t)t * 8000 + tid;
    c.ps[u]  = psP[t * NSB + s];
    c.pli[u] = pliP[off];
    c.fm[u]  = fmP[off];
    c.ev[u]  = evP[off];
  }
}

__device__ __forceinline__ void compute_chunk(
    Chunk& c, int tb, int tid,
    float& Sf, float& Ss, float& Sd,
    float kp, float ksf, float kg, float gr, float gL, float qb, float omgr,
    __half* Q)
{
  #pragma unroll
  for (int u = 0; u < 16; ++u) {
    int t = tb + u;
    float S1 = Sf + c.ps[u];
    float qf = fminf(S1, h2f(c.fm[u]));
    Sf = S1 - qf;
    float S2 = Ss + h2f(c.pli[u]) + qf - h2f(c.ev[u]);
    S2 = fmaxf(S2, 0.f);
    float qp = fmaxf(S2 - gL, 0.f) * kp;
    float qs = fminf(S2, gL) * ksf;
    Ss = S2 - qp - qs;
    float S3 = fmaf(qs, gr, Sd);
    float qd = fmaf(S3, kg, qb);
    Sd = fmaxf(S3 - qd, 0.f);
    float q = fmaf(qs, omgr, qp) + qd;
    if (t < NTT) Q[(size_t)t * 8000 + tid] = __float2half(q);
  }
}

__global__ __launch_bounds__(256, 1) void scan_kernel(
    const float* __restrict__ params,
    const unsigned short* __restrict__ pliP,
    const unsigned short* __restrict__ fmP,
    const unsigned short* __restrict__ evP,
    const float* __restrict__ psP,
    __half* __restrict__ Q)
{
  int tid = blockIdx.x * 256 + threadIdx.x;
  if (tid >= 8000) return;
  int s = tid >> 4;
  const float* P = params + tid * 6;
  float kp = P[0], ksf = P[1], kg = P[2], gr = P[3], gL = P[4], qb = P[5];
  float omgr = 1.f - gr;
  float Sf = 0.f, Ss = 0.f, Sd = 0.f;
  Chunk A, B;
  load_chunk(A, 0, s, tid, pliP, fmP, evP, psP);
  load_chunk(B, 16, s, tid, pliP, fmP, evP, psP);
  for (int tb = 0; tb < NTT; tb += 32) {
    compute_chunk(A, tb, tid, Sf, Ss, Sd, kp, ksf, kg, gr, gL, qb, omgr, Q);
    load_chunk(A, tb + 32, s, tid, pliP, fmP, evP, psP);
    compute_chunk(B, tb + 16, tid, Sf, Ss, Sd, kp, ksf, kg, gr, gL, qb, omgr, Q);
    load_chunk(B, tb + 48, s, tid, pliP, fmP, evP, psP);
  }
}

// ------------- unit-hydrograph routing + bucket mixture -------------
__global__ __launch_bounds__(128) void route_kernel(
    const __half* __restrict__ Qg, const float* __restrict__ rg,
    float* __restrict__ out)
{
  int s = blockIdx.x;
  int t0 = WARM + blockIdx.y * 128;
  int tid = threadIdx.x;
  __shared__ float Qs[143][16];
  __shared__ float rgs[16][16];   // [j][h]
  for (int i = tid; i < 143 * 16; i += 128) {
    int row = i >> 4, h = i & 15;
    int t = t0 - 15 + row; if (t > NTT - 1) t = NTT - 1;
    Qs[row][h] = __half2float(Qg[(size_t)t * 8000 + s * 16 + h]);
  }
  for (int i = tid; i < 256; i += 128) {
    int h = i >> 4, j = i & 15;
    rgs[j][h] = rg[s * 256 + i];
  }
  __syncthreads();
  int t = t0 + tid;
  if (t < NTT) {
    float acc = 0.f;
    #pragma unroll
    for (int j = 0; j < 16; ++j) {
      int row = tid + 15 - j;
      #pragma unroll
      for (int h = 0; h < 16; ++h)
        acc = fmaf(Qs[row][h], rgs[j][h], acc);
    }
    out[(t - WARM) * NSB + s] = acc;
  }
}

extern "C" void kernel_launch(void* const* d_in, const int* in_sizes, int n_in,
                              void* d_out, int out_size, void* d_ws, size_t ws_size,
                              hipStream_t stream)
{
  const float* x   = (const float*)d_in[0];
  const float* xc  = (const float*)d_in[1];
  const float* Wr1 = (const float*)d_in[2];
  const float* br1 = (const float*)d_in[3];
  const float* Wr2 = (const float*)d_in[4];
  const float* br2 = (const float*)d_in[5];
  const float* Ww1 = (const float*)d_in[6];
  const float* bw1 = (const float*)d_in[7];
  const float* Ww2 = (const float*)d_in[8];
  const float* bw2 = (const float*)d_in[9];
  const float* Wt1 = (const float*)d_in[10];
  const float* bt1 = (const float*)d_in[11];
  const float* Wt2 = (const float*)d_in[12];
  const float* bt2 = (const float*)d_in[13];

  char* w = (char*)d_ws;
  __half* pliP  = (__half*)(w);                    // 16,000,000 B
  __half* fmP   = (__half*)(w + 16000000);         // 16,000,000 B
  __half* evP   = (__half*)(w + 32000000);         // 16,000,000 B
  __half* Qg    = (__half*)(w + 48000000);         // 16,000,000 B
  float*  psP   = (float*)(w + 64000000);          //  2,000,000 B
  float*  c_g   = (float*)(w + 66000000);          //    512,000 B
  float*  params= (float*)(w + 66512000);          //    192,000 B
  float*  rgw   = (float*)(w + 66704000);          //    512,000 B
  unsigned short* BT = (unsigned short*)(w + 67216000); // 25,344 B

  prep_bt_kernel<<<48, 256, 0, stream>>>(Wt2, BT);
  static_kernel<<<500, 256, 0, stream>>>(xc, Wr1, br1, Wr2, br2,
                                         Ww1, bw1, Ww2, bw2, Wt1, bt1,
                                         c_g, params, rgw);
  tv_kernel<<<dim3(500, 16), 256, 0, stream>>>(x, Wt1, bt2, c_g, BT,
                                               pliP, fmP, evP, psP);
  scan_kernel<<<32, 256, 0, stream>>>(params, (const unsigned short*)pliP,
                                      (const unsigned short*)fmP,
                                      (const unsigned short*)evP, psP, Qg);
  route_kernel<<<dim3(500, 3), 128, 0, stream>>>(Qg, rgw, (float*)d_out);
}

// Round 2
// 280.720 us; speedup vs baseline: 1.0663x; 1.0663x over previous
//
#include <hip/hip_runtime.h>
#include <hip/hip_fp16.h>

typedef __attribute__((ext_vector_type(8))) short short8;
typedef __attribute__((ext_vector_type(8))) _Float16 half8;
typedef __attribute__((ext_vector_type(4))) float f32x4;

#define NTT 1000
#define NSB 500
#define WARM 639

__device__ __forceinline__ float fsig(float x) {
  return __builtin_amdgcn_rcpf(1.f + __expf(-x));
}
// tanh(x) = 2*sigma(2x)-1 = 2/(1+e^(-2x)) - 1 ; branchless, inf-safe
__device__ __forceinline__ float ftanh(float x) {
  float e = __expf(-2.f * x);
  return fmaf(2.f, __builtin_amdgcn_rcpf(1.f + e), -1.f);
}
__device__ __forceinline__ float h2f(unsigned short u) {
  __half_raw hr; hr.x = u;
  return __half2float((__half)hr);
}

// ------------- prep: Wt2 (256x48 f32) -> f16 transposed [48][264] -------------
__global__ void prep_bt_kernel(const float* __restrict__ Wt2,
                               _Float16* __restrict__ BT) {
  int i = blockIdx.x * 256 + threadIdx.x;
  if (i < 48 * 256) {
    int o = i >> 8, k = i & 255;
    BT[o * 264 + k] = (_Float16)Wt2[k * 48 + o];
  }
}

// ------------- prep: Wt1 rows 0..5 -> f16 [256][8] = {w0..w5,0,0} -------------
__global__ void prep_w1_kernel(const float* __restrict__ Wt1,
                               _Float16* __restrict__ W1g) {
  int k = threadIdx.x;
  half8 v = {0, 0, 0, 0, 0, 0, 0, 0};
  #pragma unroll
  for (int c = 0; c < 6; ++c) v[c] = (_Float16)Wt1[c * 256 + k];
  *(half8*)&W1g[k * 8] = v;
}

// ------------- static per-basin params (one block per basin) -------------
__global__ __launch_bounds__(256) void static_kernel(
    const float* __restrict__ xc,
    const float* __restrict__ Wr1, const float* __restrict__ br1,
    const float* __restrict__ Wr2, const float* __restrict__ br2,
    const float* __restrict__ Ww1, const float* __restrict__ bw1,
    const float* __restrict__ Ww2, const float* __restrict__ bw2,
    const float* __restrict__ Wt1, const float* __restrict__ bt1,
    float* __restrict__ c_g, float* __restrict__ params,
    float* __restrict__ rg)
{
  int s = blockIdx.x, tid = threadIdx.x;
  __shared__ float xcs[32];
  __shared__ float hw[256], hr[256];
  __shared__ float wout[112], rout[256];
  if (tid < 32) xcs[tid] = xc[s * 32 + tid];
  __syncthreads();
  {
    float aw = bw1[tid], ar = br1[tid], ac = bt1[tid];
    #pragma unroll 8
    for (int g = 0; g < 32; ++g) {
      float v = xcs[g];
      aw = fmaf(v, Ww1[g * 256 + tid], aw);
      ar = fmaf(v, Wr1[g * 256 + tid], ar);
      ac = fmaf(v, Wt1[(6 + g) * 256 + tid], ac);
    }
    hw[tid] = ftanh(aw);
    hr[tid] = ftanh(ar);
    c_g[s * 256 + tid] = ac;   // time-invariant part of layer-1 preact
  }
  __syncthreads();
  {
    float acc = br2[tid];
    #pragma unroll 8
    for (int k = 0; k < 256; ++k) acc = fmaf(hr[k], Wr2[k * 256 + tid], acc);
    rout[tid] = acc;
  }
  if (tid < 112) {
    float acc = bw2[tid];
    #pragma unroll 8
    for (int k = 0; k < 256; ++k) acc = fmaf(hw[k], Ww2[k * 112 + tid], acc);
    wout[tid] = acc;
  }
  __syncthreads();
  if (tid < 16) {
    int h = tid;
    float* P = params + (s * 16 + h) * 6;
    P[0] = fsig(wout[h * 7 + 0]);           // kp
    P[1] = fsig(wout[h * 7 + 1]);           // ksf
    P[2] = fsig(wout[h * 7 + 2]);           // kg
    P[3] = fsig(wout[h * 7 + 3]);           // gr
    P[4] = __expf(wout[h * 7 + 4]);         // gL
    P[5] = fmaxf(wout[h * 7 + 5], 0.f);     // qb
    // ga = softmax over h of wout[.*7+6]
    float m = -1e30f;
    for (int k = 0; k < 16; ++k) m = fmaxf(m, wout[k * 7 + 6]);
    float den = 0.f;
    for (int k = 0; k < 16; ++k) den += __expf(wout[k * 7 + 6] - m);
    float ga = __expf(wout[h * 7 + 6] - m) * __builtin_amdgcn_rcpf(den);
    // r = softmax over j, fused with ga -> rg
    float rm = -1e30f;
    for (int j = 0; j < 16; ++j) rm = fmaxf(rm, rout[h * 16 + j]);
    float rden = 0.f;
    for (int j = 0; j < 16; ++j) rden += __expf(rout[h * 16 + j] - rm);
    float sc = ga * __builtin_amdgcn_rcpf(rden);
    for (int j = 0; j < 16; ++j)
      rg[(s * 16 + h) * 16 + j] = __expf(rout[h * 16 + j] - rm) * sc;
  }
}

// ------------- time-varying MLP: both layers via f16 MFMA -------------
// layer1: pre[t][k] = x[t]·W1[:,k] + c_g[s][k], K padded 6(+bias)->32
// layer2: v = tanh(pre) @ Wt2, K=256
__global__ __launch_bounds__(256) void tv_kernel(
    const float* __restrict__ x, const _Float16* __restrict__ W1g,
    const float* __restrict__ bt2, const float* __restrict__ c_g,
    const _Float16* __restrict__ BTg,
    __half* __restrict__ pliP, __half* __restrict__ fmP,
    __half* __restrict__ evP, float* __restrict__ psP)
{
  int s = blockIdx.x;
  int t0 = blockIdx.y * 64;
  int tid = threadIdx.x;
  __shared__ _Float16 Abuf[64 * 256];   // hidden f16, XOR-swizzled rows
  __shared__ _Float16 Bbuf[48 * 264];   // Wt2^T f16, [n][k] pitch 264
  __shared__ _Float16 W1s[256 * 8];     // {w0..w5,0,0} per hidden col
  __shared__ _Float16 cgs[256];         // c_g[s] in f16
  __shared__ float xl[64][6];

  // ---- stage ----
  for (int i = tid; i < 1584; i += 256)          // 48*264/8
    ((half8*)Bbuf)[i] = ((const half8*)BTg)[i];
  ((half8*)W1s)[tid] = ((const half8*)W1g)[tid];
  cgs[tid] = (_Float16)c_g[s * 256 + tid];
  for (int i = tid; i < 384; i += 256) {
    int tt = i / 6, c = i % 6;
    int t = t0 + tt;
    xl[tt][c] = (t < NTT) ? x[((size_t)t * NSB + s) * 6 + c] : 0.f;
  }
  __syncthreads();

  int w = tid >> 6, l = tid & 63;

  // ---- phase 1: hidden via MFMA (K=32, only k=0..7 nonzero) ----
  {
    half8 af = {0, 0, 0, 0, 0, 0, 0, 0};
    if (l < 16) {
      const float* xr = xl[w * 16 + l];
      af[0] = (_Float16)xr[0]; af[1] = (_Float16)xr[1];
      af[2] = (_Float16)xr[2]; af[3] = (_Float16)xr[3];
      af[4] = (_Float16)xr[4]; af[5] = (_Float16)xr[5];
      af[6] = (_Float16)1.0f;  // bias slot, multiplies c_g in B
    }
    int kh0 = l & 15;
    int q = l >> 4;
    #pragma unroll
    for (int nt = 0; nt < 16; ++nt) {
      half8 bf = {0, 0, 0, 0, 0, 0, 0, 0};
      if (l < 16) {
        int kh = nt * 16 + l;
        bf = *(const half8*)&W1s[kh * 8];
        bf[6] = cgs[kh];
      }
      f32x4 pc = {0.f, 0.f, 0.f, 0.f};
      pc = __builtin_amdgcn_mfma_f32_16x16x32_f16(af, bf, pc, 0, 0, 0);
      int kh = nt * 16 + kh0;
      #pragma unroll
      for (int i = 0; i < 4; ++i) {
        int tr = w * 16 + q * 4 + i;
        float th = ftanh(pc[i]);
        int byte = (tr * 512 + kh * 2) ^ ((tr & 7) << 4);
        *(_Float16*)((char*)Abuf + byte) = (_Float16)th;
      }
    }
  }
  __syncthreads();

  // ---- phase 2: v[16 t x 48] per wave via MFMA 16x16x32 f16 ----
  int col = l & 15;
  int kb = (l >> 4) * 8;
  int arow = w * 16 + col;
  int abase = arow * 512;
  int axor = (arow & 7) << 4;
  f32x4 acc0 = {0.f, 0.f, 0.f, 0.f}, acc1 = acc0, acc2 = acc0;
  const _Float16* B0 = &Bbuf[(0 + col) * 264 + kb];
  const _Float16* B1 = &Bbuf[(16 + col) * 264 + kb];
  const _Float16* B2 = &Bbuf[(32 + col) * 264 + kb];
  #pragma unroll
  for (int ks = 0; ks < 8; ++ks) {
    half8 a = *(const half8*)((const char*)Abuf +
                              (abase + (((kb + 32 * ks) * 2) ^ axor)));
    half8 b0 = *(const half8*)(B0 + ks * 32);
    half8 b1 = *(const half8*)(B1 + ks * 32);
    half8 b2 = *(const half8*)(B2 + ks * 32);
    acc0 = __builtin_amdgcn_mfma_f32_16x16x32_f16(a, b0, acc0, 0, 0, 0);
    acc1 = __builtin_amdgcn_mfma_f32_16x16x32_f16(a, b1, acc1, 0, 0, 0);
    acc2 = __builtin_amdgcn_mfma_f32_16x16x32_f16(a, b2, acc2, 0, 0, 0);
  }
  // epilogue: C[row][col], row=(l>>4)*4+i, col=l&15
  float b2_0 = bt2[col], b2_1 = bt2[16 + col], b2_2 = bt2[32 + col];
  #pragma unroll
  for (int i = 0; i < 4; ++i) {
    int r = w * 16 + ((l >> 4) * 4) + i;
    int t = t0 + r;
    if (t >= NTT) continue;
    float Prc = xl[r][0], Evv = xl[r][1];
    float vp = fsig(0.5f * (xl[r][2] + xl[r][3]));
    float plv = Prc * vp;
    size_t base = (size_t)t * 8000 + s * 16;
    float vv0 = acc0[i] + b2_0, vv1 = acc1[i] + b2_1, vv2 = acc2[i] + b2_2;
    #pragma unroll
    for (int nt = 0; nt < 3; ++nt) {
      float v = (nt == 0) ? vv0 : (nt == 1) ? vv1 : vv2;
      int o = nt * 16 + col;
      int h = o / 3, p = o - h * 3;
      if (p == 0)      pliP[base + h] = __float2half(plv * fsig(v));       // pl*fi
      else if (p == 1) fmP [base + h] = __float2half(fmaxf(v, 0.f));       // fm
      else             evP [base + h] = __float2half(Evv * __expf(v));     // Ev
    }
  }
  if (tid < 64) {
    int t = t0 + tid;
    if (t < NTT) {
      float vp = fsig(0.5f * (xl[tid][2] + xl[tid][3]));
      psP[t * NSB + s] = xl[tid][0] * (1.f - vp);
    }
  }
}

// ------------- sequential bucket scan, 8000 chains, reg-prefetched -------------
struct Chunk {
  float ps[16];
  unsigned short pli[16], fm[16], ev[16];
};

__device__ __forceinline__ void load_chunk(
    Chunk& c, int tb, int s, int tid,
    const unsigned short* pliP, const unsigned short* fmP,
    const unsigned short* evP, const float* psP)
{
  #pragma unroll
  for (int u = 0; u < 16; ++u) {
    int t = tb + u; t = t < NTT ? t : NTT - 1;   // clamp: values discarded
    size_t off = (size_t)t * 8000 + tid;
    c.ps[u]  = psP[t * NSB + s];
    c.pli[u] = pliP[off];
    c.fm[u]  = fmP[off];
    c.ev[u]  = evP[off];
  }
}

__device__ __forceinline__ void compute_chunk(
    Chunk& c, int tb, int tid,
    float& Sf, float& Ss, float& Sd,
    float kp, float ksf, float kg, float gr, float gL, float qb, float omgr,
    __half* Q)
{
  #pragma unroll
  for (int u = 0; u < 16; ++u) {
    int t = tb + u;
    float S1 = Sf + c.ps[u];
    float qf = fminf(S1, h2f(c.fm[u]));
    Sf = S1 - qf;
    float S2 = Ss + h2f(c.pli[u]) + qf - h2f(c.ev[u]);
    S2 = fmaxf(S2, 0.f);
    float qp = fmaxf(S2 - gL, 0.f) * kp;
    float qs = fminf(S2, gL) * ksf;
    Ss = S2 - qp - qs;
    float S3 = fmaf(qs, gr, Sd);
    float qd = fmaf(S3, kg, qb);
    Sd = fmaxf(S3 - qd, 0.f);
    float q = fmaf(qs, omgr, qp) + qd;
    if (t < NTT) Q[(size_t)t * 8000 + tid] = __float2half(q);
  }
}

__global__ __launch_bounds__(256, 1) void scan_kernel(
    const float* __restrict__ params,
    const unsigned short* __restrict__ pliP,
    const unsigned short* __restrict__ fmP,
    const unsigned short* __restrict__ evP,
    const float* __restrict__ psP,
    __half* __restrict__ Q)
{
  int tid = blockIdx.x * 256 + threadIdx.x;
  if (tid >= 8000) return;
  int s = tid >> 4;
  const float* P = params + tid * 6;
  float kp = P[0], ksf = P[1], kg = P[2], gr = P[3], gL = P[4], qb = P[5];
  float omgr = 1.f - gr;
  float Sf = 0.f, Ss = 0.f, Sd = 0.f;
  Chunk A, B;
  load_chunk(A, 0, s, tid, pliP, fmP, evP, psP);
  load_chunk(B, 16, s, tid, pliP, fmP, evP, psP);
  for (int tb = 0; tb < NTT; tb += 32) {
    compute_chunk(A, tb, tid, Sf, Ss, Sd, kp, ksf, kg, gr, gL, qb, omgr, Q);
    load_chunk(A, tb + 32, s, tid, pliP, fmP, evP, psP);
    compute_chunk(B, tb + 16, tid, Sf, Ss, Sd, kp, ksf, kg, gr, gL, qb, omgr, Q);
    load_chunk(B, tb + 48, s, tid, pliP, fmP, evP, psP);
  }
}

// ------------- unit-hydrograph routing + bucket mixture -------------
__global__ __launch_bounds__(128) void route_kernel(
    const __half* __restrict__ Qg, const float* __restrict__ rg,
    float* __restrict__ out)
{
  int s = blockIdx.x;
  int t0 = WARM + blockIdx.y * 128;
  int tid = threadIdx.x;
  __shared__ float Qs[143][16];
  __shared__ float rgs[16][16];   // [j][h]
  for (int i = tid; i < 143 * 16; i += 128) {
    int row = i >> 4, h = i & 15;
    int t = t0 - 15 + row; if (t > NTT - 1) t = NTT - 1;
    Qs[row][h] = __half2float(Qg[(size_t)t * 8000 + s * 16 + h]);
  }
  for (int i = tid; i < 256; i += 128) {
    int h = i >> 4, j = i & 15;
    rgs[j][h] = rg[s * 256 + i];
  }
  __syncthreads();
  int t = t0 + tid;
  if (t < NTT) {
    float acc = 0.f;
    #pragma unroll
    for (int j = 0; j < 16; ++j) {
      int row = tid + 15 - j;
      #pragma unroll
      for (int h = 0; h < 16; ++h)
        acc = fmaf(Qs[row][h], rgs[j][h], acc);
    }
    out[(t - WARM) * NSB + s] = acc;
  }
}

extern "C" void kernel_launch(void* const* d_in, const int* in_sizes, int n_in,
                              void* d_out, int out_size, void* d_ws, size_t ws_size,
                              hipStream_t stream)
{
  const float* x   = (const float*)d_in[0];
  const float* xc  = (const float*)d_in[1];
  const float* Wr1 = (const float*)d_in[2];
  const float* br1 = (const float*)d_in[3];
  const float* Wr2 = (const float*)d_in[4];
  const float* br2 = (const float*)d_in[5];
  const float* Ww1 = (const float*)d_in[6];
  const float* bw1 = (const float*)d_in[7];
  const float* Ww2 = (const float*)d_in[8];
  const float* bw2 = (const float*)d_in[9];
  const float* Wt1 = (const float*)d_in[10];
  const float* bt1 = (const float*)d_in[11];
  const float* Wt2 = (const float*)d_in[12];
  const float* bt2 = (const float*)d_in[13];

  char* w = (char*)d_ws;
  __half* pliP  = (__half*)(w);                    // 16,000,000 B
  __half* fmP   = (__half*)(w + 16000000);         // 16,000,000 B
  __half* evP   = (__half*)(w + 32000000);         // 16,000,000 B
  __half* Qg    = (__half*)(w + 48000000);         // 16,000,000 B
  float*  psP   = (float*)(w + 64000000);          //  2,000,000 B
  float*  c_g   = (float*)(w + 66000000);          //    512,000 B
  float*  params= (float*)(w + 66512000);          //    192,000 B
  float*  rgw   = (float*)(w + 66704000);          //    512,000 B
  _Float16* BT  = (_Float16*)(w + 67216000);       //     25,344 B
  _Float16* W1g = (_Float16*)(w + 67241344);       //      4,096 B

  prep_bt_kernel<<<48, 256, 0, stream>>>(Wt2, BT);
  prep_w1_kernel<<<1, 256, 0, stream>>>(Wt1, W1g);
  static_kernel<<<500, 256, 0, stream>>>(xc, Wr1, br1, Wr2, br2,
                                         Ww1, bw1, Ww2, bw2, Wt1, bt1,
                                         c_g, params, rgw);
  tv_kernel<<<dim3(500, 16), 256, 0, stream>>>(x, W1g, bt2, c_g, BT,
                                               pliP, fmP, evP, psP);
  scan_kernel<<<32, 256, 0, stream>>>(params, (const unsigned short*)pliP,
                                      (const unsigned short*)fmP,
                                      (const unsigned short*)evP, psP, Qg);
  route_kernel<<<dim3(500, 3), 128, 0, stream>>>(Qg, rgw, (float*)d_out);
}

// Round 3
// 235.887 us; speedup vs baseline: 1.2689x; 1.1901x over previous
//
#include <hip/hip_runtime.h>
#include <hip/hip_fp16.h>

typedef __attribute__((ext_vector_type(8))) _Float16 half8;
typedef __attribute__((ext_vector_type(4))) float f32x4;
typedef __attribute__((ext_vector_type(4))) unsigned short u16x4;

#define NTT 1000
#define NSB 500
#define WARM 639

__device__ __forceinline__ float fsig(float x) {
  return __builtin_amdgcn_rcpf(1.f + __expf(-x));
}
// tanh(x) = 2/(1+e^(-2x)) - 1 ; branchless, inf-safe
__device__ __forceinline__ float ftanh(float x) {
  float e = __expf(-2.f * x);
  return fmaf(2.f, __builtin_amdgcn_rcpf(1.f + e), -1.f);
}
__device__ __forceinline__ float h2f(unsigned short u) {
  __half_raw hr; hr.x = u;
  return __half2float((__half)hr);
}

// ------------- prep: Wt2 (256x48 f32) -> f16 transposed [48][264] -------------
__global__ void prep_bt_kernel(const float* __restrict__ Wt2,
                               _Float16* __restrict__ BT) {
  int i = blockIdx.x * 256 + threadIdx.x;
  if (i < 48 * 256) {
    int o = i >> 8, k = i & 255;
    BT[o * 264 + k] = (_Float16)Wt2[k * 48 + o];
  }
}

// ------------- static per-basin params (one block per basin) -------------
__global__ __launch_bounds__(256) void static_kernel(
    const float* __restrict__ xc,
    const float* __restrict__ Wr1, const float* __restrict__ br1,
    const float* __restrict__ Wr2, const float* __restrict__ br2,
    const float* __restrict__ Ww1, const float* __restrict__ bw1,
    const float* __restrict__ Ww2, const float* __restrict__ bw2,
    const float* __restrict__ Wt1, const float* __restrict__ bt1,
    float* __restrict__ c_g, float* __restrict__ params,
    float* __restrict__ rg)
{
  int s = blockIdx.x, tid = threadIdx.x;
  __shared__ float xcs[32];
  __shared__ float hw[256], hr[256];
  __shared__ float wout[112], rout[256];
  if (tid < 32) xcs[tid] = xc[s * 32 + tid];
  __syncthreads();
  {
    float aw = bw1[tid], ar = br1[tid], ac = bt1[tid];
    #pragma unroll 8
    for (int g = 0; g < 32; ++g) {
      float v = xcs[g];
      aw = fmaf(v, Ww1[g * 256 + tid], aw);
      ar = fmaf(v, Wr1[g * 256 + tid], ar);
      ac = fmaf(v, Wt1[(6 + g) * 256 + tid], ac);
    }
    hw[tid] = ftanh(aw);
    hr[tid] = ftanh(ar);
    c_g[s * 256 + tid] = ac;   // time-invariant part of layer-1 preact
  }
  __syncthreads();
  {
    float acc = br2[tid];
    #pragma unroll 8
    for (int k = 0; k < 256; ++k) acc = fmaf(hr[k], Wr2[k * 256 + tid], acc);
    rout[tid] = acc;
  }
  if (tid < 112) {
    float acc = bw2[tid];
    #pragma unroll 8
    for (int k = 0; k < 256; ++k) acc = fmaf(hw[k], Ww2[k * 112 + tid], acc);
    wout[tid] = acc;
  }
  __syncthreads();
  if (tid < 16) {
    int h = tid;
    float* P = params + (s * 16 + h) * 6;
    P[0] = fsig(wout[h * 7 + 0]);           // kp
    P[1] = fsig(wout[h * 7 + 1]);           // ksf
    P[2] = fsig(wout[h * 7 + 2]);           // kg
    P[3] = fsig(wout[h * 7 + 3]);           // gr
    P[4] = __expf(wout[h * 7 + 4]);         // gL
    P[5] = fmaxf(wout[h * 7 + 5], 0.f);     // qb
    float m = -1e30f;
    for (int k = 0; k < 16; ++k) m = fmaxf(m, wout[k * 7 + 6]);
    float den = 0.f;
    for (int k = 0; k < 16; ++k) den += __expf(wout[k * 7 + 6] - m);
    float ga = __expf(wout[h * 7 + 6] - m) * __builtin_amdgcn_rcpf(den);
    float rm = -1e30f;
    for (int j = 0; j < 16; ++j) rm = fmaxf(rm, rout[h * 16 + j]);
    float rden = 0.f;
    for (int j = 0; j < 16; ++j) rden += __expf(rout[h * 16 + j] - rm);
    float sc = ga * __builtin_amdgcn_rcpf(rden);
    for (int j = 0; j < 16; ++j)
      rg[(s * 16 + h) * 16 + j] = __expf(rout[h * 16 + j] - rm) * sc;
  }
}

// ------------- time-varying MLP -------------
// layer1: register outer-product (lane owns 4 hidden cols), tanh, packed
//         b64 write into XOR-swizzled Abuf (wave-private rows -> no barrier)
// layer2: f16 MFMA 16x16x32, K=256
// epilogue: LDS-transpose 48 outputs/t into 8B records {pli,fm,ev,pad}
__global__ __launch_bounds__(256) void tv_kernel(
    const float* __restrict__ x, const float* __restrict__ Wt1,
    const float* __restrict__ bt2, const float* __restrict__ c_g,
    const _Float16* __restrict__ BTg,
    unsigned short* __restrict__ recP, float* __restrict__ psP)
{
  int s = blockIdx.x;
  int t0 = blockIdx.y * 64;
  int tid = threadIdx.x;
  int w = tid >> 6, l = tid & 63;

  __shared__ _Float16 Abuf[64 * 256];   // [t][kh] f16, row-XOR-swizzled
  __shared__ _Float16 Bbuf[48 * 264];   // Wt2^T f16, [n][k] pitch 264
  __shared__ float xl[64][8];           // x rows (6 used)

  // ---- stage ----
  for (int i = tid; i < 1584; i += 256)          // 48*264/8
    ((half8*)Bbuf)[i] = ((const half8*)BTg)[i];
  for (int i = tid; i < 512; i += 256) {
    int tt = i >> 3, c = i & 7;
    int t = t0 + tt;
    xl[tt][c] = (c < 6 && t < NTT) ? x[((size_t)t * NSB + s) * 6 + c] : 0.f;
  }
  // per-lane layer-1 weights: hidden cols 4l..4l+3
  f32x4 wv0 = *(const f32x4*)&Wt1[0 * 256 + 4 * l];
  f32x4 wv1 = *(const f32x4*)&Wt1[1 * 256 + 4 * l];
  f32x4 wv2 = *(const f32x4*)&Wt1[2 * 256 + 4 * l];
  f32x4 wv3 = *(const f32x4*)&Wt1[3 * 256 + 4 * l];
  f32x4 wv4 = *(const f32x4*)&Wt1[4 * 256 + 4 * l];
  f32x4 wv5 = *(const f32x4*)&Wt1[5 * 256 + 4 * l];
  f32x4 cg  = *(const f32x4*)&c_g[s * 256 + 4 * l];
  __syncthreads();

  // ---- phase 1: hidden rows w*16..w*16+15 (wave-private) ----
  #pragma unroll
  for (int tt = 0; tt < 16; ++tt) {
    int tr = w * 16 + tt;
    f32x4 xA = *(f32x4*)&xl[tr][0];
    float x4 = xl[tr][4], x5 = xl[tr][5];
    float th[4];
    #pragma unroll
    for (int j = 0; j < 4; ++j) {
      float p = cg[j];
      p = fmaf(xA[0], wv0[j], p);
      p = fmaf(xA[1], wv1[j], p);
      p = fmaf(xA[2], wv2[j], p);
      p = fmaf(xA[3], wv3[j], p);
      p = fmaf(x4,    wv4[j], p);
      p = fmaf(x5,    wv5[j], p);
      th[j] = ftanh(p);
    }
    __half2 h01 = __floats2half2_rn(th[0], th[1]);
    __half2 h23 = __floats2half2_rn(th[2], th[3]);
    uint2 pk;
    pk.x = *(unsigned int*)&h01;
    pk.y = *(unsigned int*)&h23;
    int byte = tr * 512 + ((l * 8) ^ ((tr & 7) << 4));
    *(uint2*)((char*)Abuf + byte) = pk;
  }
  // no barrier: phase 2 reads only this wave's rows (in-order DS pipe)

  // ---- phase 2: v[16 t x 48] per wave via MFMA 16x16x32 f16 ----
  int col = l & 15, q = l >> 4;
  int arow = w * 16 + col;
  int abase = arow * 512;
  int base2 = (q * 16) ^ ((arow & 7) << 4);
  f32x4 acc0 = {0.f, 0.f, 0.f, 0.f}, acc1 = acc0, acc2 = acc0;
  const _Float16* B0 = &Bbuf[(0 + col) * 264 + q * 8];
  const _Float16* B1 = &Bbuf[(16 + col) * 264 + q * 8];
  const _Float16* B2 = &Bbuf[(32 + col) * 264 + q * 8];
  #pragma unroll
  for (int ks = 0; ks < 8; ++ks) {
    half8 a = *(const half8*)((const char*)Abuf + (abase + ((ks * 64) ^ base2)));
    half8 b0 = *(const half8*)(B0 + ks * 32);
    half8 b1 = *(const half8*)(B1 + ks * 32);
    half8 b2 = *(const half8*)(B2 + ks * 32);
    acc0 = __builtin_amdgcn_mfma_f32_16x16x32_f16(a, b0, acc0, 0, 0, 0);
    acc1 = __builtin_amdgcn_mfma_f32_16x16x32_f16(a, b1, acc1, 0, 0, 0);
    acc2 = __builtin_amdgcn_mfma_f32_16x16x32_f16(a, b2, acc2, 0, 0, 0);
  }

  // ---- epilogue: transform + transpose into 8B records in scratch ----
  // scratch reuses this wave's own Abuf rows: record (t-row, h) at row*512 + h*8
  // per lane: the 3 ob's have distinct p=(col+ob)%3 -> one sig/relu/exp each
  float b2_0 = bt2[col], b2_1 = bt2[16 + col], b2_2 = bt2[32 + col];
  int c3 = col % 3;
  int ob0 = (3 - c3) % 3;              // ob with p==0
  int ob1 = (ob0 + 1) % 3;             // p==1
  int ob2 = (ob0 + 2) % 3;             // p==2
  int h0 = (16 * ob0 + col) / 3;
  int h1 = (16 * ob1 + col) / 3;
  int h2 = (16 * ob2 + col) / 3;
  #pragma unroll
  for (int i = 0; i < 4; ++i) {
    int tr = w * 16 + q * 4 + i;
    int t = t0 + tr;
    if (t >= NTT) continue;
    f32x4 xr = *(f32x4*)&xl[tr][0];
    float Prc = xr[0], Evv = xr[1];
    float vp = fsig(0.5f * (xr[2] + xr[3]));
    float plv = Prc * vp;
    float vv0 = acc0[i] + b2_0, vv1 = acc1[i] + b2_1, vv2 = acc2[i] + b2_2;
    float s0 = (ob0 == 0) ? vv0 : (ob0 == 1) ? vv1 : vv2;
    float s1 = (ob1 == 0) ? vv0 : (ob1 == 1) ? vv1 : vv2;
    float s2 = (ob2 == 0) ? vv0 : (ob2 == 1) ? vv1 : vv2;
    char* rowp = (char*)Abuf + tr * 512;
    *(__half*)(rowp + h0 * 8 + 0) = __float2half(plv * fsig(s0));   // pli
    *(__half*)(rowp + h1 * 8 + 2) = __float2half(fmaxf(s1, 0.f));   // fm
    *(__half*)(rowp + h2 * 8 + 4) = __float2half(Evv * __expf(s2)); // ev
  }
  // read back 8B records, store to global (wave-private rows, in-order DS)
  #pragma unroll
  for (int k2 = 0; k2 < 4; ++k2) {
    int idx = k2 * 64 + l;             // 0..255 over wave's 16t x 16h
    int tt = idx >> 4, h = idx & 15;
    int tr = w * 16 + tt;
    int t = t0 + tr;
    if (t < NTT) {
      u16x4 r4 = *(const u16x4*)((const char*)Abuf + (tr * 512 + h * 8));
      *(u16x4*)&recP[((size_t)t * 8000 + s * 16 + h) * 4] = r4;
    }
  }
  if (tid < 64) {
    int t = t0 + tid;
    if (t < NTT) {
      float vp = fsig(0.5f * (xl[tid][2] + xl[tid][3]));
      psP[t * NSB + s] = xl[tid][0] * (1.f - vp);
    }
  }
}

// ------------- sequential bucket scan, 8000 chains, reg-prefetched -------------
struct Chunk {
  float ps[16];
  uint2 rec[16];
};

__device__ __forceinline__ void load_chunk(
    Chunk& c, int tb, int s, int tid,
    const uint2* recP, const float* psP)
{
  #pragma unroll
  for (int u = 0; u < 16; ++u) {
    int t = tb + u; t = t < NTT ? t : NTT - 1;   // clamp: values discarded
    c.ps[u]  = psP[t * NSB + s];
    c.rec[u] = recP[(size_t)t * 8000 + tid];
  }
}

__device__ __forceinline__ void compute_chunk(
    Chunk& c, int tb, int tid,
    float& Sf, float& Ss, float& Sd,
    float kp, float ksf, float kg, float gr, float gL, float qb, float omgr,
    __half* Q)
{
  #pragma unroll
  for (int u = 0; u < 16; ++u) {
    int t = tb + u;
    float pli = h2f((unsigned short)(c.rec[u].x & 0xffff));
    float fm  = h2f((unsigned short)(c.rec[u].x >> 16));
    float ev  = h2f((unsigned short)(c.rec[u].y & 0xffff));
    float S1 = Sf + c.ps[u];
    float qf = fminf(S1, fm);
    Sf = S1 - qf;
    float S2 = Ss + pli + qf - ev;
    S2 = fmaxf(S2, 0.f);
    float qp = fmaxf(S2 - gL, 0.f) * kp;
    float qs = fminf(S2, gL) * ksf;
    Ss = S2 - qp - qs;
    float S3 = fmaf(qs, gr, Sd);
    float qd = fmaf(S3, kg, qb);
    Sd = fmaxf(S3 - qd, 0.f);
    float q = fmaf(qs, omgr, qp) + qd;
    if (t < NTT) Q[(size_t)t * 8000 + tid] = __float2half(q);
  }
}

__global__ __launch_bounds__(256, 1) void scan_kernel(
    const float* __restrict__ params,
    const uint2* __restrict__ recP,
    const float* __restrict__ psP,
    __half* __restrict__ Q)
{
  int tid = blockIdx.x * 256 + threadIdx.x;
  if (tid >= 8000) return;
  int s = tid >> 4;
  const float* P = params + tid * 6;
  float kp = P[0], ksf = P[1], kg = P[2], gr = P[3], gL = P[4], qb = P[5];
  float omgr = 1.f - gr;
  float Sf = 0.f, Ss = 0.f, Sd = 0.f;
  Chunk A, B;
  load_chunk(A, 0, s, tid, recP, psP);
  load_chunk(B, 16, s, tid, recP, psP);
  for (int tb = 0; tb < NTT; tb += 32) {
    compute_chunk(A, tb, tid, Sf, Ss, Sd, kp, ksf, kg, gr, gL, qb, omgr, Q);
    load_chunk(A, tb + 32, s, tid, recP, psP);
    compute_chunk(B, tb + 16, tid, Sf, Ss, Sd, kp, ksf, kg, gr, gL, qb, omgr, Q);
    load_chunk(B, tb + 48, s, tid, recP, psP);
  }
}

// ------------- unit-hydrograph routing + bucket mixture -------------
__global__ __launch_bounds__(128) void route_kernel(
    const __half* __restrict__ Qg, const float* __restrict__ rg,
    float* __restrict__ out)
{
  int s = blockIdx.x;
  int t0 = WARM + blockIdx.y * 128;
  int tid = threadIdx.x;
  __shared__ float Qs[143][16];
  __shared__ float rgs[16][16];   // [j][h]
  for (int i = tid; i < 143 * 16; i += 128) {
    int row = i >> 4, h = i & 15;
    int t = t0 - 15 + row; if (t > NTT - 1) t = NTT - 1;
    Qs[row][h] = __half2float(Qg[(size_t)t * 8000 + s * 16 + h]);
  }
  for (int i = tid; i < 256; i += 128) {
    int h = i >> 4, j = i & 15;
    rgs[j][h] = rg[s * 256 + i];
  }
  __syncthreads();
  int t = t0 + tid;
  if (t < NTT) {
    float acc = 0.f;
    #pragma unroll
    for (int j = 0; j < 16; ++j) {
      int row = tid + 15 - j;
      #pragma unroll
      for (int h = 0; h < 16; ++h)
        acc = fmaf(Qs[row][h], rgs[j][h], acc);
    }
    out[(t - WARM) * NSB + s] = acc;
  }
}

extern "C" void kernel_launch(void* const* d_in, const int* in_sizes, int n_in,
                              void* d_out, int out_size, void* d_ws, size_t ws_size,
                              hipStream_t stream)
{
  const float* x   = (const float*)d_in[0];
  const float* xc  = (const float*)d_in[1];
  const float* Wr1 = (const float*)d_in[2];
  const float* br1 = (const float*)d_in[3];
  const float* Wr2 = (const float*)d_in[4];
  const float* br2 = (const float*)d_in[5];
  const float* Ww1 = (const float*)d_in[6];
  const float* bw1 = (const float*)d_in[7];
  const float* Ww2 = (const float*)d_in[8];
  const float* bw2 = (const float*)d_in[9];
  const float* Wt1 = (const float*)d_in[10];
  const float* bt1 = (const float*)d_in[11];
  const float* Wt2 = (const float*)d_in[12];
  const float* bt2 = (const float*)d_in[13];

  char* w = (char*)d_ws;
  unsigned short* recP = (unsigned short*)(w);     // 64,000,000 B (8B/record)
  __half* Qg    = (__half*)(w + 64000000);         // 16,000,000 B
  float*  psP   = (float*)(w + 80000000);          //  2,000,000 B
  float*  c_g   = (float*)(w + 82000000);          //    512,000 B
  float*  params= (float*)(w + 82512000);          //    192,000 B
  float*  rgw   = (float*)(w + 82704000);          //    512,000 B
  _Float16* BT  = (_Float16*)(w + 83216000);       //     25,344 B

  prep_bt_kernel<<<48, 256, 0, stream>>>(Wt2, BT);
  static_kernel<<<500, 256, 0, stream>>>(xc, Wr1, br1, Wr2, br2,
                                         Ww1, bw1, Ww2, bw2, Wt1, bt1,
                                         c_g, params, rgw);
  tv_kernel<<<dim3(500, 16), 256, 0, stream>>>(x, Wt1, bt2, c_g, BT,
                                               recP, psP);
  scan_kernel<<<32, 256, 0, stream>>>(params, (const uint2*)recP, psP, Qg);
  route_kernel<<<dim3(500, 3), 128, 0, stream>>>(Qg, rgw, (float*)d_out);
}

// Round 5
// 207.395 us; speedup vs baseline: 1.4433x; 1.1374x over previous
//
#include <hip/hip_runtime.h>
#include <hip/hip_fp16.h>

typedef __attribute__((ext_vector_type(8))) _Float16 half8;
typedef __attribute__((ext_vector_type(2))) _Float16 h2v;
typedef __attribute__((ext_vector_type(4))) float f32x4;
typedef __attribute__((ext_vector_type(4))) unsigned short u16x4;

#define NTT 1000
#define NSB 500
#define WARM 639

__device__ __forceinline__ float fsig(float x) {
  return __builtin_amdgcn_rcpf(1.f + __expf(-x));
}
// tanh(x) = 2/(1+e^(-2x)) - 1 ; branchless, inf-safe (f32)
__device__ __forceinline__ float ftanh(float x) {
  float e = __expf(-2.f * x);
  return fmaf(2.f, __builtin_amdgcn_rcpf(1.f + e), -1.f);
}
__device__ __forceinline__ float h2f(unsigned short u) {
  __half_raw hr; hr.x = u;
  return __half2float((__half)hr);
}
__device__ __forceinline__ __half2 u2h(unsigned int u) {
  __half2 h; *(unsigned int*)&h = u; return h;
}
__device__ __forceinline__ unsigned int h2u(__half2 h) {
  return *(unsigned int*)&h;
}
// packed f16 min (no __hmin2 in HIP headers) -> v_pk_min_f16
__device__ __forceinline__ __half2 hmin2(__half2 a, __half2 b) {
  h2v av = *(h2v*)&a, bv = *(h2v*)&b;
  h2v r = __builtin_elementwise_min(av, bv);
  return *(__half2*)&r;
}

// ---- prep: Wt2 (256x48 f32) -> f16 transposed, XOR-swizzled [48][256] ----
__global__ void prep_bt_kernel(const float* __restrict__ Wt2,
                               _Float16* __restrict__ BT) {
  int i = blockIdx.x * 256 + threadIdx.x;
  if (i < 48 * 256) {
    int o = i >> 8, k = i & 255;
    int byte = o * 512 + ((k * 2) ^ ((o & 7) << 4));
    *(_Float16*)((char*)BT + byte) = (_Float16)Wt2[k * 48 + o];
  }
}

// ------------- static per-basin params (one block per basin) -------------
__global__ __launch_bounds__(256) void static_kernel(
    const float* __restrict__ xc,
    const float* __restrict__ Wr1, const float* __restrict__ br1,
    const float* __restrict__ Wr2, const float* __restrict__ br2,
    const float* __restrict__ Ww1, const float* __restrict__ bw1,
    const float* __restrict__ Ww2, const float* __restrict__ bw2,
    const float* __restrict__ Wt1, const float* __restrict__ bt1,
    float* __restrict__ c_g, float* __restrict__ params,
    float* __restrict__ rg)
{
  int s = blockIdx.x, tid = threadIdx.x;
  __shared__ float xcs[32];
  __shared__ float hw[256], hr[256];
  __shared__ float wout[112], rout[256];
  if (tid < 32) xcs[tid] = xc[s * 32 + tid];
  __syncthreads();
  {
    float aw = bw1[tid], ar = br1[tid], ac = bt1[tid];
    #pragma unroll 8
    for (int g = 0; g < 32; ++g) {
      float v = xcs[g];
      aw = fmaf(v, Ww1[g * 256 + tid], aw);
      ar = fmaf(v, Wr1[g * 256 + tid], ar);
      ac = fmaf(v, Wt1[(6 + g) * 256 + tid], ac);
    }
    hw[tid] = ftanh(aw);
    hr[tid] = ftanh(ar);
    c_g[s * 256 + tid] = ac;   // time-invariant part of layer-1 preact
  }
  __syncthreads();
  {
    float acc = br2[tid];
    #pragma unroll 8
    for (int k = 0; k < 256; ++k) acc = fmaf(hr[k], Wr2[k * 256 + tid], acc);
    rout[tid] = acc;
  }
  if (tid < 112) {
    float acc = bw2[tid];
    #pragma unroll 8
    for (int k = 0; k < 256; ++k) acc = fmaf(hw[k], Ww2[k * 112 + tid], acc);
    wout[tid] = acc;
  }
  __syncthreads();
  if (tid < 16) {
    int h = tid;
    float* P = params + (s * 16 + h) * 6;
    P[0] = fsig(wout[h * 7 + 0]);           // kp
    P[1] = fsig(wout[h * 7 + 1]);           // ksf
    P[2] = fsig(wout[h * 7 + 2]);           // kg
    P[3] = fsig(wout[h * 7 + 3]);           // gr
    P[4] = __expf(wout[h * 7 + 4]);         // gL
    P[5] = fmaxf(wout[h * 7 + 5], 0.f);     // qb
    float m = -1e30f;
    for (int k = 0; k < 16; ++k) m = fmaxf(m, wout[k * 7 + 6]);
    float den = 0.f;
    for (int k = 0; k < 16; ++k) den += __expf(wout[k * 7 + 6] - m);
    float ga = __expf(wout[h * 7 + 6] - m) * __builtin_amdgcn_rcpf(den);
    float rm = -1e30f;
    for (int j = 0; j < 16; ++j) rm = fmaxf(rm, rout[h * 16 + j]);
    float rden = 0.f;
    for (int j = 0; j < 16; ++j) rden += __expf(rout[h * 16 + j] - rm);
    float sc = ga * __builtin_amdgcn_rcpf(rden);
    for (int j = 0; j < 16; ++j)
      rg[(s * 16 + h) * 16 + j] = __expf(rout[h * 16 + j] - rm) * sc;
  }
}

// ------------- time-varying MLP -------------
// layer1: packed-f16 outer product, two K=128 half-passes into a 4KB/wave
//         XOR-swizzled transpose buffer (wave-private -> no barrier)
// layer2: f16 MFMA 16x16x32, K=256 (accumulated across both halves)
// epilogue: transform + LDS-transpose into 8B records {pli,fm,ev,ps}
__global__ __launch_bounds__(256, 3) void tv_kernel(
    const float* __restrict__ x, const float* __restrict__ Wt1,
    const float* __restrict__ bt2, const float* __restrict__ c_g,
    const _Float16* __restrict__ BTg,
    unsigned short* __restrict__ recP)
{
  int s = blockIdx.x;
  int t0 = blockIdx.y * 64;
  int tid = threadIdx.x;
  int w = tid >> 6, l = tid & 63;

  __shared__ _Float16 Abuf[4][16][128];   // 16 KB: per-wave transpose buf
  __shared__ _Float16 Bbuf[48 * 256];     // 24 KB: Wt2^T, pre-swizzled
  __shared__ __half2  xl2[64][8];         // 2 KB: broadcast x pairs (6 used)
  __shared__ float    xe[64][4];          // 1 KB: {plv, Evp, psn, 0}

  // ---- stage ----
  for (int i = tid; i < 1536; i += 256)          // 48*256/8
    ((half8*)Bbuf)[i] = ((const half8*)BTg)[i];
  if (tid < 64) {
    int t = t0 + tid;
    float2 a = {0.f, 0.f}, b = a, c = a;
    if (t < NTT) {
      const float* xp = &x[((size_t)t * NSB + s) * 6];
      a = *(const float2*)(xp + 0);   // Prcp, Evp
      b = *(const float2*)(xp + 2);   // T1, T2
      c = *(const float2*)(xp + 4);
    }
    float vp = fsig(0.5f * (b.x + b.y));
    xe[tid][0] = a.x * vp;            // pl
    xe[tid][1] = a.y;                 // Evp
    xe[tid][2] = a.x * (1.f - vp);    // ps
    xe[tid][3] = 0.f;
    xl2[tid][0] = __floats2half2_rn(a.x, a.x);
    xl2[tid][1] = __floats2half2_rn(a.y, a.y);
    xl2[tid][2] = __floats2half2_rn(b.x, b.x);
    xl2[tid][3] = __floats2half2_rn(b.y, b.y);
    xl2[tid][4] = __floats2half2_rn(c.x, c.x);
    xl2[tid][5] = __floats2half2_rn(c.y, c.y);
    xl2[tid][6] = __floats2half2_rn(0.f, 0.f);
    xl2[tid][7] = __floats2half2_rn(0.f, 0.f);
  }
  __syncthreads();

  // constants
  const __half2 one2 = __floats2half2_rn(1.f, 1.f);
  const __half2 mk2  = __floats2half2_rn(-2.88539008f, -2.88539008f); // -2*log2(e)
  const __half2 hi2  = __floats2half2_rn(15.5f, 15.5f);

  // per-lane layer-1 weights for both halves (cols 2l,2l+1 and +128)
  __half2 wlo[6], whi[6];
  #pragma unroll
  for (int c = 0; c < 6; ++c) {
    float2 g0 = *(const float2*)&Wt1[c * 256 + 2 * l];
    float2 g1 = *(const float2*)&Wt1[c * 256 + 128 + 2 * l];
    wlo[c] = __floats2half2_rn(g0.x, g0.y);
    whi[c] = __floats2half2_rn(g1.x, g1.y);
  }
  float2 cg0 = *(const float2*)&c_g[s * 256 + 2 * l];
  float2 cg1 = *(const float2*)&c_g[s * 256 + 128 + 2 * l];
  __half2 cglo = __floats2half2_rn(cg0.x, cg0.y);
  __half2 cghi = __floats2half2_rn(cg1.x, cg1.y);

  char* aw_base = (char*)&Abuf[w][0][0];
  int col = l & 15, q = l >> 4;
  int arow_xor = (col & 7) << 4;
  const char* Bb = (const char*)Bbuf;
  int r0 = 0 + col, r1 = 16 + col, r2 = 32 + col;
  f32x4 acc0 = {0.f, 0.f, 0.f, 0.f}, acc1 = acc0, acc2 = acc0;

  #pragma unroll
  for (int half = 0; half < 2; ++half) {
    const __half2* wv = half ? whi : wlo;
    __half2 cg2 = half ? cghi : cglo;
    // ---- phase 1: this wave's 16 rows, 128 cols ----
    #pragma unroll
    for (int tt = 0; tt < 16; ++tt) {
      int tr = w * 16 + tt;
      uint4 xa = *(const uint4*)&xl2[tr][0];
      uint2 xb = *(const uint2*)&xl2[tr][4];
      __half2 acc = cg2;
      acc = __hfma2(u2h(xa.x), wv[0], acc);
      acc = __hfma2(u2h(xa.y), wv[1], acc);
      acc = __hfma2(u2h(xa.z), wv[2], acc);
      acc = __hfma2(u2h(xa.w), wv[3], acc);
      acc = __hfma2(u2h(xb.x), wv[4], acc);
      acc = __hfma2(u2h(xb.y), wv[5], acc);
      __half2 t2 = hmin2(__hmul2(acc, mk2), hi2);
      __half2 e = h2exp2(t2);
      __half2 th = __hmul2(__hsub2(one2, e), h2rcp(__hadd2(one2, e)));
      int byte = tt * 256 + ((4 * l) ^ ((tt & 7) << 4));
      *(unsigned int*)(aw_base + byte) = h2u(th);
    }
    // no barrier: wave-private rows, in-order DS pipe
    // ---- phase 2: 4 K-steps of MFMA on this half ----
    #pragma unroll
    for (int ks = 0; ks < 4; ++ks) {
      int kof = ks * 64 + q * 16;           // byte offset of k-chunk in half
      int kob = half * 256 + kof;           // byte offset within full K row
      half8 a  = *(const half8*)(aw_base + col * 256 + (kof ^ arow_xor));
      half8 b0 = *(const half8*)(Bb + r0 * 512 + (kob ^ ((r0 & 7) << 4)));
      half8 b1 = *(const half8*)(Bb + r1 * 512 + (kob ^ ((r1 & 7) << 4)));
      half8 b2 = *(const half8*)(Bb + r2 * 512 + (kob ^ ((r2 & 7) << 4)));
      acc0 = __builtin_amdgcn_mfma_f32_16x16x32_f16(a, b0, acc0, 0, 0, 0);
      acc1 = __builtin_amdgcn_mfma_f32_16x16x32_f16(a, b1, acc1, 0, 0, 0);
      acc2 = __builtin_amdgcn_mfma_f32_16x16x32_f16(a, b2, acc2, 0, 0, 0);
    }
  }

  // ---- epilogue: transform + transpose into 8B records in wave scratch ----
  // record (tt, h) at aw_base + tt*128 + h*8 ; per lane the 3 outs have
  // distinct p=(col+ob)%3 -> exactly one sig / relu / exp each
  float b2_0 = bt2[col], b2_1 = bt2[16 + col], b2_2 = bt2[32 + col];
  int c3 = col % 3;
  int ob0 = (3 - c3) % 3;              // ob with p==0
  int ob1 = (ob0 + 1) % 3;             // p==1
  int ob2 = (ob0 + 2) % 3;             // p==2
  int h0 = (16 * ob0 + col) / 3;
  int h1 = (16 * ob1 + col) / 3;
  int h2 = (16 * ob2 + col) / 3;
  #pragma unroll
  for (int i = 0; i < 4; ++i) {
    int tt = q * 4 + i;
    int t = t0 + w * 16 + tt;
    if (t >= NTT) continue;
    float2 pe = *(const float2*)&xe[w * 16 + tt][0];  // plv, Evp
    float vv0 = acc0[i] + b2_0, vv1 = acc1[i] + b2_1, vv2 = acc2[i] + b2_2;
    float s0 = (ob0 == 0) ? vv0 : (ob0 == 1) ? vv1 : vv2;
    float s1 = (ob1 == 0) ? vv0 : (ob1 == 1) ? vv1 : vv2;
    float s2 = (ob2 == 0) ? vv0 : (ob2 == 1) ? vv1 : vv2;
    char* rowp = aw_base + tt * 128;
    *(__half*)(rowp + h0 * 8 + 0) = __float2half(pe.x * fsig(s0));   // pli
    *(__half*)(rowp + h1 * 8 + 2) = __float2half(fmaxf(s1, 0.f));    // fm
    *(__half*)(rowp + h2 * 8 + 4) = __float2half(pe.y * __expf(s2)); // ev
  }
  // read back 8B records, insert ps, store to global (wave-private rows)
  #pragma unroll
  for (int k2 = 0; k2 < 4; ++k2) {
    int idx = k2 * 64 + l;             // 0..255 over wave's 16t x 16h
    int tt = idx >> 4, h = idx & 15;
    int t = t0 + w * 16 + tt;
    if (t < NTT) {
      u16x4 r4 = *(const u16x4*)(aw_base + tt * 128 + h * 8);
      __half psh = __float2half(xe[w * 16 + tt][2]);
      r4[3] = *(unsigned short*)&psh;
      *(u16x4*)&recP[((size_t)t * 8000 + s * 16 + h) * 4] = r4;
    }
  }
}

// ------------- sequential bucket scan, 8000 chains, reg-prefetched -------------
struct Chunk {
  uint2 rec[16];
};

__device__ __forceinline__ void load_chunk(
    Chunk& c, int tb, int tid, const uint2* recP)
{
  #pragma unroll
  for (int u = 0; u < 16; ++u) {
    int t = tb + u; t = t < NTT ? t : NTT - 1;   // clamp: values discarded
    c.rec[u] = recP[(size_t)t * 8000 + tid];
  }
}

__device__ __forceinline__ void compute_chunk(
    Chunk& c, int tb, int tid,
    float& Sf, float& Ss, float& Sd,
    float kp, float ksf, float kg, float gr, float gL, float qb, float omgr,
    __half* Q)
{
  #pragma unroll
  for (int u = 0; u < 16; ++u) {
    int t = tb + u;
    float pli = h2f((unsigned short)(c.rec[u].x & 0xffff));
    float fm  = h2f((unsigned short)(c.rec[u].x >> 16));
    float ev  = h2f((unsigned short)(c.rec[u].y & 0xffff));
    float ps  = h2f((unsigned short)(c.rec[u].y >> 16));
    float S1 = Sf + ps;
    float qf = fminf(S1, fm);
    Sf = S1 - qf;
    float S2 = Ss + pli + qf - ev;
    S2 = fmaxf(S2, 0.f);
    float qp = fmaxf(S2 - gL, 0.f) * kp;
    float qs = fminf(S2, gL) * ksf;
    Ss = S2 - qp - qs;
    float S3 = fmaf(qs, gr, Sd);
    float qd = fmaf(S3, kg, qb);
    Sd = fmaxf(S3 - qd, 0.f);
    float q = fmaf(qs, omgr, qp) + qd;
    if (t < NTT) Q[(size_t)t * 8000 + tid] = __float2half(q);
  }
}

__global__ __launch_bounds__(64, 1) void scan_kernel(
    const float* __restrict__ params,
    const uint2* __restrict__ recP,
    __half* __restrict__ Q)
{
  int tid = blockIdx.x * 64 + threadIdx.x;   // 125 blocks x 64 = 8000
  const float* P = params + tid * 6;
  float kp = P[0], ksf = P[1], kg = P[2], gr = P[3], gL = P[4], qb = P[5];
  float omgr = 1.f - gr;
  float Sf = 0.f, Ss = 0.f, Sd = 0.f;
  Chunk A, B;
  load_chunk(A, 0, tid, recP);
  load_chunk(B, 16, tid, recP);
  for (int tb = 0; tb < NTT; tb += 32) {
    compute_chunk(A, tb, tid, Sf, Ss, Sd, kp, ksf, kg, gr, gL, qb, omgr, Q);
    load_chunk(A, tb + 32, tid, recP);
    compute_chunk(B, tb + 16, tid, Sf, Ss, Sd, kp, ksf, kg, gr, gL, qb, omgr, Q);
    load_chunk(B, tb + 48, tid, recP);
  }
}

// ------------- unit-hydrograph routing + bucket mixture -------------
__global__ __launch_bounds__(128) void route_kernel(
    const __half* __restrict__ Qg, const float* __restrict__ rg,
    float* __restrict__ out)
{
  int s = blockIdx.x;
  int t0 = WARM + blockIdx.y * 128;
  int tid = threadIdx.x;
  __shared__ float Qs[143][16];
  __shared__ float rgs[16][16];   // [j][h]
  for (int i = tid; i < 143 * 16; i += 128) {
    int row = i >> 4, h = i & 15;
    int t = t0 - 15 + row; if (t > NTT - 1) t = NTT - 1;
    Qs[row][h] = __half2float(Qg[(size_t)t * 8000 + s * 16 + h]);
  }
  for (int i = tid; i < 256; i += 128) {
    int h = i >> 4, j = i & 15;
    rgs[j][h] = rg[s * 256 + i];
  }
  __syncthreads();
  int t = t0 + tid;
  if (t < NTT) {
    float acc = 0.f;
    #pragma unroll
    for (int j = 0; j < 16; ++j) {
      int row = tid + 15 - j;
      #pragma unroll
      for (int h = 0; h < 16; ++h)
        acc = fmaf(Qs[row][h], rgs[j][h], acc);
    }
    out[(t - WARM) * NSB + s] = acc;
  }
}

extern "C" void kernel_launch(void* const* d_in, const int* in_sizes, int n_in,
                              void* d_out, int out_size, void* d_ws, size_t ws_size,
                              hipStream_t stream)
{
  const float* x   = (const float*)d_in[0];
  const float* xc  = (const float*)d_in[1];
  const float* Wr1 = (const float*)d_in[2];
  const float* br1 = (const float*)d_in[3];
  const float* Wr2 = (const float*)d_in[4];
  const float* br2 = (const float*)d_in[5];
  const float* Ww1 = (const float*)d_in[6];
  const float* bw1 = (const float*)d_in[7];
  const float* Ww2 = (const float*)d_in[8];
  const float* bw2 = (const float*)d_in[9];
  const float* Wt1 = (const float*)d_in[10];
  const float* bt1 = (const float*)d_in[11];
  const float* Wt2 = (const float*)d_in[12];
  const float* bt2 = (const float*)d_in[13];

  char* w = (char*)d_ws;
  unsigned short* recP = (unsigned short*)(w);     // 64,000,000 B (8B/record)
  __half* Qg    = (__half*)(w + 64000000);         // 16,000,000 B
  float*  c_g   = (float*)(w + 80000000);          //    512,000 B
  float*  params= (float*)(w + 80512000);          //    192,000 B
  float*  rgw   = (float*)(w + 80704000);          //    512,000 B
  _Float16* BT  = (_Float16*)(w + 81216000);       //     24,576 B

  prep_bt_kernel<<<48, 256, 0, stream>>>(Wt2, BT);
  static_kernel<<<500, 256, 0, stream>>>(xc, Wr1, br1, Wr2, br2,
                                         Ww1, bw1, Ww2, bw2, Wt1, bt1,
                                         c_g, params, rgw);
  tv_kernel<<<dim3(500, 16), 256, 0, stream>>>(x, Wt1, bt2, c_g, BT, recP);
  scan_kernel<<<125, 64, 0, stream>>>(params, (const uint2*)recP, Qg);
  route_kernel<<<dim3(500, 3), 128, 0, stream>>>(Qg, rgw, (float*)d_out);
}

// Round 6
// 205.463 us; speedup vs baseline: 1.4568x; 1.0094x over previous
//
#include <hip/hip_runtime.h>
#include <hip/hip_fp16.h>

typedef __attribute__((ext_vector_type(8))) _Float16 half8;
typedef __attribute__((ext_vector_type(2))) _Float16 h2v;
typedef __attribute__((ext_vector_type(4))) float f32x4;
typedef __attribute__((ext_vector_type(4))) unsigned short u16x4;

#define NTT 1000
#define NSB 500
#define WARM 639

__device__ __forceinline__ float fsig(float x) {
  return __builtin_amdgcn_rcpf(1.f + __expf(-x));
}
// tanh(x) = 2/(1+e^(-2x)) - 1 ; branchless, inf-safe (f32)
__device__ __forceinline__ float ftanh(float x) {
  float e = __expf(-2.f * x);
  return fmaf(2.f, __builtin_amdgcn_rcpf(1.f + e), -1.f);
}
__device__ __forceinline__ float h2f(unsigned short u) {
  __half_raw hr; hr.x = u;
  return __half2float((__half)hr);
}
__device__ __forceinline__ __half2 u2h(unsigned int u) {
  __half2 h; *(unsigned int*)&h = u; return h;
}
__device__ __forceinline__ unsigned int h2u(__half2 h) {
  return *(unsigned int*)&h;
}
// packed f16 min (no __hmin2 in HIP headers) -> v_pk_min_f16
__device__ __forceinline__ __half2 hmin2(__half2 a, __half2 b) {
  h2v av = *(h2v*)&a, bv = *(h2v*)&b;
  h2v r = __builtin_elementwise_min(av, bv);
  return *(__half2*)&r;
}

// ---- prep: Wt2 (256x48 f32) -> f16 transposed, XOR-swizzled [48][256] ----
__global__ void prep_bt_kernel(const float* __restrict__ Wt2,
                               _Float16* __restrict__ BT) {
  int i = blockIdx.x * 256 + threadIdx.x;
  if (i < 48 * 256) {
    int o = i >> 8, k = i & 255;
    int byte = o * 512 + ((k * 2) ^ ((o & 7) << 4));
    *(_Float16*)((char*)BT + byte) = (_Float16)Wt2[k * 48 + o];
  }
}

// ------------- static per-basin params (one block per basin) -------------
__global__ __launch_bounds__(256) void static_kernel(
    const float* __restrict__ xc,
    const float* __restrict__ Wr1, const float* __restrict__ br1,
    const float* __restrict__ Wr2, const float* __restrict__ br2,
    const float* __restrict__ Ww1, const float* __restrict__ bw1,
    const float* __restrict__ Ww2, const float* __restrict__ bw2,
    const float* __restrict__ Wt1, const float* __restrict__ bt1,
    float* __restrict__ c_g, float* __restrict__ params,
    float* __restrict__ rg)
{
  int s = blockIdx.x, tid = threadIdx.x;
  __shared__ float xcs[32];
  __shared__ float hw[256], hr[256];
  __shared__ float wout[112], rout[256];
  if (tid < 32) xcs[tid] = xc[s * 32 + tid];
  __syncthreads();
  {
    float aw = bw1[tid], ar = br1[tid], ac = bt1[tid];
    #pragma unroll 8
    for (int g = 0; g < 32; ++g) {
      float v = xcs[g];
      aw = fmaf(v, Ww1[g * 256 + tid], aw);
      ar = fmaf(v, Wr1[g * 256 + tid], ar);
      ac = fmaf(v, Wt1[(6 + g) * 256 + tid], ac);
    }
    hw[tid] = ftanh(aw);
    hr[tid] = ftanh(ar);
    c_g[s * 256 + tid] = ac;   // time-invariant part of layer-1 preact
  }
  __syncthreads();
  {
    float acc = br2[tid];
    #pragma unroll 8
    for (int k = 0; k < 256; ++k) acc = fmaf(hr[k], Wr2[k * 256 + tid], acc);
    rout[tid] = acc;
  }
  if (tid < 112) {
    float acc = bw2[tid];
    #pragma unroll 8
    for (int k = 0; k < 256; ++k) acc = fmaf(hw[k], Ww2[k * 112 + tid], acc);
    wout[tid] = acc;
  }
  __syncthreads();
  if (tid < 16) {
    int h = tid;
    float* P = params + (s * 16 + h) * 6;
    P[0] = fsig(wout[h * 7 + 0]);           // kp
    P[1] = fsig(wout[h * 7 + 1]);           // ksf
    P[2] = fsig(wout[h * 7 + 2]);           // kg
    P[3] = fsig(wout[h * 7 + 3]);           // gr
    P[4] = __expf(wout[h * 7 + 4]);         // gL
    P[5] = fmaxf(wout[h * 7 + 5], 0.f);     // qb
    float m = -1e30f;
    for (int k = 0; k < 16; ++k) m = fmaxf(m, wout[k * 7 + 6]);
    float den = 0.f;
    for (int k = 0; k < 16; ++k) den += __expf(wout[k * 7 + 6] - m);
    float ga = __expf(wout[h * 7 + 6] - m) * __builtin_amdgcn_rcpf(den);
    float rm = -1e30f;
    for (int j = 0; j < 16; ++j) rm = fmaxf(rm, rout[h * 16 + j]);
    float rden = 0.f;
    for (int j = 0; j < 16; ++j) rden += __expf(rout[h * 16 + j] - rm);
    float sc = ga * __builtin_amdgcn_rcpf(rden);
    for (int j = 0; j < 16; ++j)
      rg[(s * 16 + h) * 16 + j] = __expf(rout[h * 16 + j] - rm) * sc;
  }
}

// ------------- time-varying MLP -------------
// layer1: packed-f16 outer product, two K=128 half-passes into a 4KB/wave
//         XOR-swizzled transpose buffer (wave-private -> no barrier)
// layer2: f16 MFMA 16x16x32, K=256 (accumulated across both halves)
// epilogue: transform + LDS-transpose into 8B records {pli,fm,ev,ps}
__global__ __launch_bounds__(256, 3) void tv_kernel(
    const float* __restrict__ x, const float* __restrict__ Wt1,
    const float* __restrict__ bt2, const float* __restrict__ c_g,
    const _Float16* __restrict__ BTg,
    unsigned short* __restrict__ recP)
{
  int s = blockIdx.x;
  int t0 = blockIdx.y * 64;
  int tid = threadIdx.x;
  int w = tid >> 6, l = tid & 63;

  __shared__ _Float16 Abuf[4][16][128];   // 16 KB: per-wave transpose buf
  __shared__ _Float16 Bbuf[48 * 256];     // 24 KB: Wt2^T, pre-swizzled
  __shared__ __half2  xl2[64][8];         // 2 KB: broadcast x pairs (6 used)
  __shared__ float    xe[64][4];          // 1 KB: {plv, Evp, psn, 0}

  // ---- stage ----
  for (int i = tid; i < 1536; i += 256)          // 48*256/8
    ((half8*)Bbuf)[i] = ((const half8*)BTg)[i];
  if (tid < 64) {
    int t = t0 + tid;
    float2 a = {0.f, 0.f}, b = a, c = a;
    if (t < NTT) {
      const float* xp = &x[((size_t)t * NSB + s) * 6];
      a = *(const float2*)(xp + 0);   // Prcp, Evp
      b = *(const float2*)(xp + 2);   // T1, T2
      c = *(const float2*)(xp + 4);
    }
    float vp = fsig(0.5f * (b.x + b.y));
    xe[tid][0] = a.x * vp;            // pl
    xe[tid][1] = a.y;                 // Evp
    xe[tid][2] = a.x * (1.f - vp);    // ps
    xe[tid][3] = 0.f;
    xl2[tid][0] = __floats2half2_rn(a.x, a.x);
    xl2[tid][1] = __floats2half2_rn(a.y, a.y);
    xl2[tid][2] = __floats2half2_rn(b.x, b.x);
    xl2[tid][3] = __floats2half2_rn(b.y, b.y);
    xl2[tid][4] = __floats2half2_rn(c.x, c.x);
    xl2[tid][5] = __floats2half2_rn(c.y, c.y);
    xl2[tid][6] = __floats2half2_rn(0.f, 0.f);
    xl2[tid][7] = __floats2half2_rn(0.f, 0.f);
  }
  __syncthreads();

  // constants
  const __half2 one2 = __floats2half2_rn(1.f, 1.f);
  const __half2 mk2  = __floats2half2_rn(-2.88539008f, -2.88539008f); // -2*log2(e)
  const __half2 hi2  = __floats2half2_rn(15.5f, 15.5f);

  // per-lane layer-1 weights for both halves (cols 2l,2l+1 and +128)
  __half2 wlo[6], whi[6];
  #pragma unroll
  for (int c = 0; c < 6; ++c) {
    float2 g0 = *(const float2*)&Wt1[c * 256 + 2 * l];
    float2 g1 = *(const float2*)&Wt1[c * 256 + 128 + 2 * l];
    wlo[c] = __floats2half2_rn(g0.x, g0.y);
    whi[c] = __floats2half2_rn(g1.x, g1.y);
  }
  float2 cg0 = *(const float2*)&c_g[s * 256 + 2 * l];
  float2 cg1 = *(const float2*)&c_g[s * 256 + 128 + 2 * l];
  __half2 cglo = __floats2half2_rn(cg0.x, cg0.y);
  __half2 cghi = __floats2half2_rn(cg1.x, cg1.y);

  char* aw_base = (char*)&Abuf[w][0][0];
  int col = l & 15, q = l >> 4;
  int arow_xor = (col & 7) << 4;
  const char* Bb = (const char*)Bbuf;
  int r0 = 0 + col, r1 = 16 + col, r2 = 32 + col;
  f32x4 acc0 = {0.f, 0.f, 0.f, 0.f}, acc1 = acc0, acc2 = acc0;

  #pragma unroll
  for (int half = 0; half < 2; ++half) {
    const __half2* wv = half ? whi : wlo;
    __half2 cg2 = half ? cghi : cglo;
    // ---- phase 1: this wave's 16 rows, 128 cols ----
    #pragma unroll
    for (int tt = 0; tt < 16; ++tt) {
      int tr = w * 16 + tt;
      uint4 xa = *(const uint4*)&xl2[tr][0];
      uint2 xb = *(const uint2*)&xl2[tr][4];
      __half2 acc = cg2;
      acc = __hfma2(u2h(xa.x), wv[0], acc);
      acc = __hfma2(u2h(xa.y), wv[1], acc);
      acc = __hfma2(u2h(xa.z), wv[2], acc);
      acc = __hfma2(u2h(xa.w), wv[3], acc);
      acc = __hfma2(u2h(xb.x), wv[4], acc);
      acc = __hfma2(u2h(xb.y), wv[5], acc);
      __half2 t2 = hmin2(__hmul2(acc, mk2), hi2);
      __half2 e = h2exp2(t2);
      __half2 th = __hmul2(__hsub2(one2, e), h2rcp(__hadd2(one2, e)));
      int byte = tt * 256 + ((4 * l) ^ ((tt & 7) << 4));
      *(unsigned int*)(aw_base + byte) = h2u(th);
    }
    // no barrier: wave-private rows, in-order DS pipe
    // ---- phase 2: 4 K-steps of MFMA on this half ----
    #pragma unroll
    for (int ks = 0; ks < 4; ++ks) {
      int kof = ks * 64 + q * 16;           // byte offset of k-chunk in half
      int kob = half * 256 + kof;           // byte offset within full K row
      half8 a  = *(const half8*)(aw_base + col * 256 + (kof ^ arow_xor));
      half8 b0 = *(const half8*)(Bb + r0 * 512 + (kob ^ ((r0 & 7) << 4)));
      half8 b1 = *(const half8*)(Bb + r1 * 512 + (kob ^ ((r1 & 7) << 4)));
      half8 b2 = *(const half8*)(Bb + r2 * 512 + (kob ^ ((r2 & 7) << 4)));
      acc0 = __builtin_amdgcn_mfma_f32_16x16x32_f16(a, b0, acc0, 0, 0, 0);
      acc1 = __builtin_amdgcn_mfma_f32_16x16x32_f16(a, b1, acc1, 0, 0, 0);
      acc2 = __builtin_amdgcn_mfma_f32_16x16x32_f16(a, b2, acc2, 0, 0, 0);
    }
  }

  // ---- epilogue: transform + transpose into 8B records in wave scratch ----
  // record (tt, h) at aw_base + tt*128 + h*8 ; per lane the 3 outs have
  // distinct p=(col+ob)%3 -> exactly one sig / relu / exp each
  float b2_0 = bt2[col], b2_1 = bt2[16 + col], b2_2 = bt2[32 + col];
  int c3 = col % 3;
  int ob0 = (3 - c3) % 3;              // ob with p==0
  int ob1 = (ob0 + 1) % 3;             // p==1
  int ob2 = (ob0 + 2) % 3;             // p==2
  int h0 = (16 * ob0 + col) / 3;
  int h1 = (16 * ob1 + col) / 3;
  int h2 = (16 * ob2 + col) / 3;
  #pragma unroll
  for (int i = 0; i < 4; ++i) {
    int tt = q * 4 + i;
    int t = t0 + w * 16 + tt;
    if (t >= NTT) continue;
    float2 pe = *(const float2*)&xe[w * 16 + tt][0];  // plv, Evp
    float vv0 = acc0[i] + b2_0, vv1 = acc1[i] + b2_1, vv2 = acc2[i] + b2_2;
    float s0 = (ob0 == 0) ? vv0 : (ob0 == 1) ? vv1 : vv2;
    float s1 = (ob1 == 0) ? vv0 : (ob1 == 1) ? vv1 : vv2;
    float s2 = (ob2 == 0) ? vv0 : (ob2 == 1) ? vv1 : vv2;
    char* rowp = aw_base + tt * 128;
    *(__half*)(rowp + h0 * 8 + 0) = __float2half(pe.x * fsig(s0));   // pli
    *(__half*)(rowp + h1 * 8 + 2) = __float2half(fmaxf(s1, 0.f));    // fm
    *(__half*)(rowp + h2 * 8 + 4) = __float2half(pe.y * __expf(s2)); // ev
  }
  // read back 8B records, insert ps, store to global (wave-private rows)
  #pragma unroll
  for (int k2 = 0; k2 < 4; ++k2) {
    int idx = k2 * 64 + l;             // 0..255 over wave's 16t x 16h
    int tt = idx >> 4, h = idx & 15;
    int t = t0 + w * 16 + tt;
    if (t < NTT) {
      u16x4 r4 = *(const u16x4*)(aw_base + tt * 128 + h * 8);
      __half psh = __float2half(xe[w * 16 + tt][2]);
      r4[3] = *(unsigned short*)&psh;
      *(u16x4*)&recP[((size_t)t * 8000 + s * 16 + h) * 4] = r4;
    }
  }
}

// ------------- sequential bucket scan, 8000 chains, reg-prefetched -------------
struct Chunk {
  uint2 rec[16];
};

__device__ __forceinline__ void load_chunk(
    Chunk& c, int tb, int tid, const uint2* recP)
{
  #pragma unroll
  for (int u = 0; u < 16; ++u) {
    int t = tb + u; t = t < NTT ? t : NTT - 1;   // clamp: values discarded
    c.rec[u] = recP[(size_t)t * 8000 + tid];
  }
}

__device__ __forceinline__ void compute_chunk(
    Chunk& c, int tb, int tid,
    float& Sf, float& Ss, float& Sd,
    float kp, float ksf, float kg, float gr, float gL, float qb, float omgr,
    __half* Q)
{
  #pragma unroll
  for (int u = 0; u < 16; ++u) {
    int t = tb + u;
    float pli = h2f((unsigned short)(c.rec[u].x & 0xffff));
    float fm  = h2f((unsigned short)(c.rec[u].x >> 16));
    float ev  = h2f((unsigned short)(c.rec[u].y & 0xffff));
    float ps  = h2f((unsigned short)(c.rec[u].y >> 16));
    float ce  = pli - ev;                 // off the dependency chain
    float S1 = Sf + ps;
    float qf = fminf(S1, fm);
    Sf = S1 - qf;
    float S2 = fmaxf((Ss + ce) + qf, 0.f);
    float qp = fmaxf(S2 - gL, 0.f) * kp;
    float qs = fminf(S2, gL) * ksf;
    Ss = S2 - qp - qs;
    float S3 = fmaf(qs, gr, Sd);
    float qd = fmaf(S3, kg, qb);
    Sd = fmaxf(S3 - qd, 0.f);
    float q = fmaf(qs, omgr, qp) + qd;
    if (t < NTT) Q[(size_t)t * 8000 + tid] = __float2half(q);
  }
}

__global__ __launch_bounds__(64, 1) void scan_kernel(
    const float* __restrict__ params,
    const uint2* __restrict__ recP,
    __half* __restrict__ Q)
{
  int tid = blockIdx.x * 64 + threadIdx.x;   // 125 blocks x 64 = 8000
  const float* P = params + tid * 6;
  float kp = P[0], ksf = P[1], kg = P[2], gr = P[3], gL = P[4], qb = P[5];
  float omgr = 1.f - gr;
  float Sf = 0.f, Ss = 0.f, Sd = 0.f;
  Chunk A, B;
  load_chunk(A, 0, tid, recP);
  load_chunk(B, 16, tid, recP);
  for (int tb = 0; tb < NTT; tb += 32) {
    compute_chunk(A, tb, tid, Sf, Ss, Sd, kp, ksf, kg, gr, gL, qb, omgr, Q);
    load_chunk(A, tb + 32, tid, recP);
    compute_chunk(B, tb + 16, tid, Sf, Ss, Sd, kp, ksf, kg, gr, gL, qb, omgr, Q);
    load_chunk(B, tb + 48, tid, recP);
  }
}

// ------------- unit-hydrograph routing + bucket mixture -------------
// Qs pitch = 17 floats (odd, coprime with 32 banks): consecutive rows sweep
// all banks -> the [row-varying, h-fixed] read pattern is conflict-free
// (was pitch 16 -> 2 banks for 64 lanes = 32-way conflict, ~11x serialization)
__global__ __launch_bounds__(128) void route_kernel(
    const __half* __restrict__ Qg, const float* __restrict__ rg,
    float* __restrict__ out)
{
  int s = blockIdx.x;
  int t0 = WARM + blockIdx.y * 128;
  int tid = threadIdx.x;
  __shared__ float Qs[143][17];
  __shared__ float rgs[16][16];   // [j][h]
  for (int i = tid; i < 143 * 16; i += 128) {
    int row = i >> 4, h = i & 15;
    int t = t0 - 15 + row; if (t > NTT - 1) t = NTT - 1;
    Qs[row][h] = __half2float(Qg[(size_t)t * 8000 + s * 16 + h]);
  }
  for (int i = tid; i < 256; i += 128) {
    int h = i >> 4, j = i & 15;
    rgs[j][h] = rg[s * 256 + i];
  }
  __syncthreads();
  int t = t0 + tid;
  if (t < NTT) {
    float acc = 0.f;
    #pragma unroll
    for (int j = 0; j < 16; ++j) {
      int row = tid + 15 - j;
      #pragma unroll
      for (int h = 0; h < 16; ++h)
        acc = fmaf(Qs[row][h], rgs[j][h], acc);
    }
    out[(t - WARM) * NSB + s] = acc;
  }
}

extern "C" void kernel_launch(void* const* d_in, const int* in_sizes, int n_in,
                              void* d_out, int out_size, void* d_ws, size_t ws_size,
                              hipStream_t stream)
{
  const float* x   = (const float*)d_in[0];
  const float* xc  = (const float*)d_in[1];
  const float* Wr1 = (const float*)d_in[2];
  const float* br1 = (const float*)d_in[3];
  const float* Wr2 = (const float*)d_in[4];
  const float* br2 = (const float*)d_in[5];
  const float* Ww1 = (const float*)d_in[6];
  const float* bw1 = (const float*)d_in[7];
  const float* Ww2 = (const float*)d_in[8];
  const float* bw2 = (const float*)d_in[9];
  const float* Wt1 = (const float*)d_in[10];
  const float* bt1 = (const float*)d_in[11];
  const float* Wt2 = (const float*)d_in[12];
  const float* bt2 = (const float*)d_in[13];

  char* w = (char*)d_ws;
  unsigned short* recP = (unsigned short*)(w);     // 64,000,000 B (8B/record)
  __half* Qg    = (__half*)(w + 64000000);         // 16,000,000 B
  float*  c_g   = (float*)(w + 80000000);          //    512,000 B
  float*  params= (float*)(w + 80512000);          //    192,000 B
  float*  rgw   = (float*)(w + 80704000);          //    512,000 B
  _Float16* BT  = (_Float16*)(w + 81216000);       //     24,576 B

  prep_bt_kernel<<<48, 256, 0, stream>>>(Wt2, BT);
  static_kernel<<<500, 256, 0, stream>>>(xc, Wr1, br1, Wr2, br2,
                                         Ww1, bw1, Ww2, bw2, Wt1, bt1,
                                         c_g, params, rgw);
  tv_kernel<<<dim3(500, 16), 256, 0, stream>>>(x, Wt1, bt2, c_g, BT, recP);
  scan_kernel<<<125, 64, 0, stream>>>(params, (const uint2*)recP, Qg);
  route_kernel<<<dim3(500, 3), 128, 0, stream>>>(Qg, rgw, (float*)d_out);
}